// Round 3
// baseline (81.370 us; speedup 1.0000x reference)
//
#include <hip/hip_runtime.h>
#include <math.h>

#define B 2
#define S 1024
#define H 1024
#define NIN 512
#define NP 32
#define SC 16            // s-chunks for ctx partials
#define SCHUNK (S / SC)  // 64

// ---------- K1: fused template-norm + act-norm + pattern + nrm partials ----------
// grid = B*S/8 = 256 blocks; block 256 = 8 tokens x 32 sub-lanes
__global__ __launch_bounds__(256)
void k_pattern(const float* __restrict__ act, const float* __restrict__ tmpl,
               float* __restrict__ P, float* __restrict__ nrm) {
    __shared__ float act_lds[8][NIN];   // 16 KB
    __shared__ float invn[NP];
    __shared__ float psum[8][NP];
    int tid = threadIdx.x;
    int t0 = blockIdx.x * 8;            // first token (global b*S+s)
    int b  = t0 >> 10;

    // stage 8 act rows as float4 (coalesced, conflict-free)
    {
        const float4* src = (const float4*)(act + (size_t)t0 * NIN);
        float4* dst = (float4*)(&act_lds[0][0]);
        for (int k = tid; k < 8 * NIN / 4; k += 256) dst[k] = src[k];
    }
    // template inverse norms: 8 lanes per template (tmpl is L2-resident)
    {
        int n = tid >> 3, s8 = tid & 7;
        const float* tr = tmpl + (size_t)n * NIN;
        float ss = 0.f;
#pragma unroll 16
        for (int k = 0; k < 64; ++k) { float x = tr[s8 + 8 * k]; ss += x * x; }
        ss += __shfl_xor(ss, 1); ss += __shfl_xor(ss, 2); ss += __shfl_xor(ss, 4);
        if (s8 == 0) invn[n] = 1.f / fmaxf(sqrtf(ss), 1e-12f);
    }
    __syncthreads();

    int tok = tid >> 5;   // 0..7
    int sub = tid & 31;   // 0..31
    // act row inverse norm (32 lanes of this token cooperate; conflict-free)
    float ss = 0.f;
#pragma unroll
    for (int k = 0; k < 16; ++k) { float x = act_lds[tok][sub + 32 * k]; ss += x * x; }
#pragma unroll
    for (int m = 16; m; m >>= 1) ss += __shfl_xor(ss, m);
    float inva = 1.f / fmaxf(sqrtf(ss), 1e-12f);

    // interleaved slice: this lane owns elems {sub*4 + q*128 + e}, e=0..3
    // -> LDS reads are lane-contiguous float4 (conflict-free), 4 per thread
    float4 av[4];
#pragma unroll
    for (int q = 0; q < 4; ++q)
        av[q] = *(const float4*)(&act_lds[tok][sub * 4 + q * 128]);

    float dot[NP];
#pragma unroll
    for (int n = 0; n < NP; ++n) {
        const float* tr = tmpl + (size_t)n * NIN + sub * 4;
        float d = 0.f;
#pragma unroll
        for (int q = 0; q < 4; ++q) {
            float4 tv = *(const float4*)(tr + q * 128);  // coalesced 512B/32 lanes
            d += tv.x * av[q].x + tv.y * av[q].y + tv.z * av[q].z + tv.w * av[q].w;
        }
        dot[n] = d;
    }
    // reduce each dot across the 32-lane group; lane sub keeps n==sub
    float myd = 0.f;
#pragma unroll
    for (int n = 0; n < NP; ++n) {
        float d = dot[n];
        d += __shfl_xor(d, 1); d += __shfl_xor(d, 2); d += __shfl_xor(d, 4);
        d += __shfl_xor(d, 8); d += __shfl_xor(d, 16);
        if (sub == n) myd = d;
    }
    float p = 1.f / (1.f + expf(-myd * inva * invn[sub]));
    P[(size_t)(t0 + tok) * NP + sub] = p;
    psum[tok][sub] = p;
    __syncthreads();
    if (tid < NP) {
        float s = 0.f;
#pragma unroll
        for (int t = 0; t < 8; ++t) s += psum[t][tid];
        unsafeAtomicAdd(&nrm[b * NP + tid], s);
    }
}

// ---------- K2: partial contexts; P via scalar loads (wave-uniform address) ----------
// grid = B * SC * 8 = 256; block 256 = 128 h x 2 n-groups of 16
__global__ __launch_bounds__(256)
void k_ctx_partial(const float* __restrict__ I, const float* __restrict__ P,
                   float* __restrict__ part) {
    int bid = blockIdx.x;
    int ht = bid & 7;
    int sc = (bid >> 3) & (SC - 1);
    int b  = bid >> 7;
    int tid = threadIdx.x;
    int hl = tid & 127;
    int g  = __builtin_amdgcn_readfirstlane(tid >> 7);  // wave-uniform -> s_load P
    int h  = ht * 128 + hl;
    int s0 = sc * SCHUNK;
    const float* Pb = P + ((size_t)b * S + s0) * NP + g * 16;
    const float* Ip = I + ((size_t)b * S + s0) * H + h;
    float acc[16];
#pragma unroll
    for (int j = 0; j < 16; ++j) acc[j] = 0.f;
#pragma unroll 4
    for (int s = 0; s < SCHUNK; ++s) {
        float x = Ip[(size_t)s * H];
#pragma unroll
        for (int j = 0; j < 16; ++j) acc[j] += x * Pb[s * NP + j];
    }
    size_t base = (((size_t)b * SC + sc) * NP + g * 16) * H + h;
#pragma unroll
    for (int j = 0; j < 16; ++j) part[base + (size_t)j * H] = acc[j];
}

// ---------- K3: ctx[b,n,h] = sum_sc part ----------
__global__ __launch_bounds__(256)
void k_ctx_reduce(const float* __restrict__ part, float* __restrict__ ctx) {
    int idx = blockIdx.x * 256 + threadIdx.x;   // 0 .. B*NP*H-1
    int b = idx >> 15;                          // NP*H = 32768
    int rem = idx & 32767;
    float s = 0.f;
#pragma unroll
    for (int sc = 0; sc < SC; ++sc)
        s += part[((size_t)b * SC + sc) * (NP * H) + rem];
    ctx[idx] = s;
}

// ---------- K4: T[b,n,k] = sum_h (ctx[b,n,h]/nrm[b,n]) * W[n,k,h] ----------
// grid = NP*64 = 2048; block 256 = 4 waves, 4 W-rows per wave, no LDS
__global__ __launch_bounds__(256, 4)
void k_transform(const float* __restrict__ W, const float* __restrict__ ctx,
                 const float* __restrict__ nrm, float* __restrict__ T) {
    int bid = blockIdx.x;
    int n  = bid >> 6;     // 0..31
    int rg = bid & 63;     // row-group of 16
    int tid = threadIdx.x;
    int w = tid >> 6, lane = tid & 63;

    float inv0 = 1.f / (nrm[n] + 1e-8f);
    float inv1 = 1.f / (nrm[NP + n] + 1e-8f);

    const float4* c0g = (const float4*)(ctx + (size_t)n * H);
    const float4* c1g = (const float4*)(ctx + ((size_t)NP + n) * H);
    float4 c0[4], c1[4];
#pragma unroll
    for (int it = 0; it < 4; ++it) {
        float4 v = c0g[it * 64 + lane];
        c0[it] = make_float4(v.x * inv0, v.y * inv0, v.z * inv0, v.w * inv0);
        float4 u = c1g[it * 64 + lane];
        c1[it] = make_float4(u.x * inv1, u.y * inv1, u.z * inv1, u.w * inv1);
    }

    int row0 = rg * 16 + w * 4;
    const float4* Wr = (const float4*)(W + ((size_t)n * H + row0) * H);
    float a0[4] = {0.f, 0.f, 0.f, 0.f};
    float a1[4] = {0.f, 0.f, 0.f, 0.f};
#pragma unroll
    for (int it = 0; it < 4; ++it) {
#pragma unroll
        for (int r = 0; r < 4; ++r) {
            float4 wv = Wr[r * 256 + it * 64 + lane];
            a0[r] += wv.x * c0[it].x + wv.y * c0[it].y + wv.z * c0[it].z + wv.w * c0[it].w;
            a1[r] += wv.x * c1[it].x + wv.y * c1[it].y + wv.z * c1[it].z + wv.w * c1[it].w;
        }
    }
#pragma unroll
    for (int r = 0; r < 4; ++r) {
#pragma unroll
        for (int off = 32; off; off >>= 1) {
            a0[r] += __shfl_xor(a0[r], off);
            a1[r] += __shfl_xor(a1[r], off);
        }
    }
    if (lane == 0) {
#pragma unroll
        for (int r = 0; r < 4; ++r) {
            T[(size_t)n * H + row0 + r] = a0[r];
            T[((size_t)NP + n) * H + row0 + r] = a1[r];
        }
    }
}

// ---------- K5: combined[b,s,h] = sum_n T[b,n,h] * P[b,s,n]; P via scalar loads ----------
// grid = B * 64 * 4 = 512; block 256, thread owns one h
__global__ __launch_bounds__(256)
void k_combine(const float* __restrict__ T, const float* __restrict__ P,
               float* __restrict__ out) {
    int bid = blockIdx.x;
    int ht = bid & 3;          // h-tile of 256
    int sc = (bid >> 2) & 63;  // s-tile of 16
    int b  = bid >> 8;
    int tid = threadIdx.x;
    __shared__ float Tl[NP][256];   // 32 KB
    int h0 = ht * 256;
    for (int k = tid; k < NP * 256; k += 256) {
        int n = k >> 8, h = k & 255;
        Tl[n][h] = T[((size_t)b * NP + n) * H + h0 + h];
    }
    __syncthreads();
    int s0 = sc * 16;
    const float* Pb = P + ((size_t)b * S + s0) * NP;   // block-uniform -> s_load
    float acc[16];
#pragma unroll
    for (int s = 0; s < 16; ++s) acc[s] = 0.f;
#pragma unroll
    for (int n0 = 0; n0 < NP; n0 += 4) {
        float t0v = Tl[n0 + 0][tid];
        float t1v = Tl[n0 + 1][tid];
        float t2v = Tl[n0 + 2][tid];
        float t3v = Tl[n0 + 3][tid];
#pragma unroll
        for (int s = 0; s < 16; ++s) {
            const float* pr = Pb + s * NP + n0;
            acc[s] += t0v * pr[0] + t1v * pr[1] + t2v * pr[2] + t3v * pr[3];
        }
    }
#pragma unroll
    for (int s = 0; s < 16; ++s)
        out[((size_t)b * S + s0 + s) * H + h0 + tid] = acc[s];
}

extern "C" void kernel_launch(void* const* d_in, const int* in_sizes, int n_in,
                              void* d_out, int out_size, void* d_ws, size_t ws_size,
                              hipStream_t stream) {
    const float* I    = (const float*)d_in[0];  // [B,S,H]
    const float* act  = (const float*)d_in[1];  // [B,S,NIN]
    const float* tmpl = (const float*)d_in[2];  // [NP,NIN]
    const float* W    = (const float*)d_in[3];  // [NP*H,H]
    float* out  = (float*)d_out;                // combined [B,S,H]
    float* Pout = out + (size_t)B * S * H;      // process_activations [B,S,NP]

    float* ws   = (float*)d_ws;
    float* nrm  = ws;                                   // B*NP = 64
    float* part = nrm + 64;                             // B*SC*NP*H = 1M floats
    float* ctx  = part + (size_t)B * SC * NP * H;       // B*NP*H
    float* T    = ctx + (size_t)B * NP * H;             // B*NP*H

    hipMemsetAsync(nrm, 0, (size_t)B * NP * sizeof(float), stream);
    k_pattern    <<<B * S / 8,            256, 0, stream>>>(act, tmpl, Pout, nrm);
    k_ctx_partial<<<B * SC * 8,           256, 0, stream>>>(I, Pout, part);
    k_ctx_reduce <<<B * NP * H / 256,     256, 0, stream>>>(part, ctx);
    k_transform  <<<NP * 64,              256, 0, stream>>>(W, ctx, nrm, T);
    k_combine    <<<B * 64 * 4,           256, 0, stream>>>(T, Pout, out);
}